// Round 5
// baseline (377.710 us; speedup 1.0000x reference)
//
#include <hip/hip_runtime.h>
#include <cstdint>
#include <cstddef>
#include <math.h>

// Problem: x(64,16,1152) w(16,16,1152,64) b(1152,64) -> out(64,16,64), f32.
// u = einsum(BCD,cCDd->BcDd); scores = sum_c u^2 / 4; attn = softmax_D(scores);
// out = einsum(BDd,BcDd->Bcd, attn + b, u).  Flash-style online softmax over D.
#define CDd 1179648   // c stride in w  (16*1152*64)
#define Dd_ 73728     // C stride in w  (1152*64)
#define XB_ 18432     // B stride in x  (16*1152)
#define NCHUNK 128
#define DSTEP 9       // 1152 / NCHUNK

__device__ __forceinline__ void async_dword(float* lds, const float* g) {
  __builtin_amdgcn_global_load_lds(
      (const __attribute__((address_space(1))) void*)g,
      (__attribute__((address_space(3))) void*)lds, 4, 0, 0);
}

// Kernel 1: fused projection + scores + online softmax + weighted accumulation
// over one D-chunk of 9, for all 64 B x 16 c x 16 d (one dtile of 4).
// 512 threads, 8B x 4c per-thread tile. LDS ~70 KB -> 2 blocks/CU;
// __launch_bounds__(512,4) pins VGPR <= 128 (4 waves/SIMD) for 2-block occupancy.
__global__ __launch_bounds__(512, 4)
void caps_k1(const float* __restrict__ x, const float* __restrict__ w,
             const float* __restrict__ bias,
             float* __restrict__ psacc, float* __restrict__ pt,
             float* __restrict__ pm, float* __restrict__ pl)
{
  __shared__ __align__(16) float ws[2][16 * 256];     // [C][dl*16+c], dbuf
  __shared__ __align__(16) float xs[16 * DSTEP * 64]; // [C][dd][b], once/chunk
  __shared__ __align__(16) float bs[DSTEP * 16];      // [dd][dl],  once/chunk

  const int tid  = threadIdx.x;
  const int lane = tid & 63;
  const int wv   = tid >> 6;        // wave 0..7
  const int b0   = (tid & 7) * 8;   // 8 B per thread
  const int c0   = ((tid >> 3) & 3) * 4; // 4 c per thread
  const int dl   = tid >> 5;        // d-within-tile 0..15

  const int dt = blockIdx.x >> 7;   // dtile 0..3 (16 d each)
  const int ch = blockIdx.x & 127;  // D-chunk; 4 dt of same ch share an XCD
  const int D0 = ch * DSTEP;

  const int wlane = (lane & 15) * CDd + (lane >> 4); // c*CDd + dl_sub

  // ---- once-per-chunk staging: x transpose-gather + bias ----
  for (int cc = 0; cc < 2; ++cc) {
    const int C = wv * 2 + cc;
    const float* gx = x + (size_t)lane * XB_ + C * 1152 + D0;
#pragma unroll
    for (int dd = 0; dd < DSTEP; ++dd)
      async_dword(&xs[(C * DSTEP + dd) * 64], gx + dd);
  }
  if (wv == 0) {
#pragma unroll
    for (int it = 0; it < 3; ++it) {
      const int flat = it * 64 + lane;
      if (flat < DSTEP * 16)
        async_dword(&bs[it * 64],
                    bias + (size_t)(D0 + (flat >> 4)) * 64 + dt * 16 + (flat & 15));
    }
  }

  auto stage_ws = [&](int s, int dd) {
#pragma unroll
    for (int cc = 0; cc < 2; ++cc) {
      const int C = wv * 2 + cc;
      const float* gw = w + (size_t)wlane + (size_t)C * Dd_
                          + (size_t)(D0 + dd) * 64 + dt * 16;
#pragma unroll
      for (int j = 0; j < 4; ++j)   // ws[C][dl*16+c] built by transpose gather
        async_dword(&ws[s][C * 256 + j * 64], gw + 4 * j);
    }
  };

  float sacc[8][4], tacc[8][4], m2[8], l[8];
#pragma unroll
  for (int i = 0; i < 8; ++i) {
    m2[i] = -INFINITY; l[i] = 0.f;
#pragma unroll
    for (int j = 0; j < 4; ++j) { sacc[i][j] = 0.f; tacc[i][j] = 0.f; }
  }

  stage_ws(0, 0);
  __syncthreads();
  int cur = 0;

  for (int dd = 0; dd < DSTEP; ++dd) {
    if (dd + 1 < DSTEP) stage_ws(cur ^ 1, dd + 1);  // async prefetch next D

    const float* wsT = ws[cur];
    const float bb = bs[dd * 16 + dl];

    float u[8][4];
#pragma unroll
    for (int C = 0; C < 16; ++C) {
      const float4 a0 = *(const float4*)&xs[(C * DSTEP + dd) * 64 + b0];
      const float4 a1 = *(const float4*)&xs[(C * DSTEP + dd) * 64 + b0 + 4];
      const float4 w0 = *(const float4*)&wsT[C * 256 + dl * 16 + c0];
      const float av[8] = {a0.x, a0.y, a0.z, a0.w, a1.x, a1.y, a1.z, a1.w};
      const float wn[4] = {w0.x, w0.y, w0.z, w0.w};
#pragma unroll
      for (int i = 0; i < 8; ++i)
#pragma unroll
        for (int j = 0; j < 4; ++j)
          u[i][j] = (C == 0) ? av[i] * wn[j] : fmaf(av[i], wn[j], u[i][j]);
    }

#pragma unroll
    for (int i = 0; i < 8; ++i) {
      float ps = 0.f;
#pragma unroll
      for (int j = 0; j < 4; ++j) ps = fmaf(u[i][j], u[i][j], ps);
      ps += __shfl_xor(ps, 8);       // sum over the 4 c-quarters
      ps += __shfl_xor(ps, 16);
      const float s2 = ps * 0.36067376022224085f;  // log2(e)/NC, NC=4
      const float mn = fmaxf(m2[i], s2);
      const float sc = exp2f(m2[i] - mn);
      const float p  = exp2f(s2 - mn);
      m2[i] = mn;
      l[i]  = fmaf(l[i], sc, p);
#pragma unroll
      for (int j = 0; j < 4; ++j) {
        sacc[i][j] = fmaf(sacc[i][j], sc, p * u[i][j]); // attn part (unnorm.)
        tacc[i][j] = fmaf(bb, u[i][j], tacc[i][j]);     // bias part (exact)
      }
    }
    __syncthreads();
    cur ^= 1;
  }

  // partials: psacc/pt [ch][dt][dl][c][b]; pm/pl [ch][dt][dl][b]
  const size_t rowB = (size_t)(ch * 4 + dt) * 16 + dl;
#pragma unroll
  for (int j = 0; j < 4; ++j) {
    const size_t off = (rowB * 16 + (c0 + j)) * 64 + b0;
    *(float4*)&psacc[off]     = make_float4(sacc[0][j], sacc[1][j], sacc[2][j], sacc[3][j]);
    *(float4*)&psacc[off + 4] = make_float4(sacc[4][j], sacc[5][j], sacc[6][j], sacc[7][j]);
    *(float4*)&pt[off]        = make_float4(tacc[0][j], tacc[1][j], tacc[2][j], tacc[3][j]);
    *(float4*)&pt[off + 4]    = make_float4(tacc[4][j], tacc[5][j], tacc[6][j], tacc[7][j]);
  }
  if (c0 == 0) {
    const size_t off = rowB * 64 + b0;
    *(float4*)&pm[off]     = make_float4(m2[0], m2[1], m2[2], m2[3]);
    *(float4*)&pm[off + 4] = make_float4(m2[4], m2[5], m2[6], m2[7]);
    *(float4*)&pl[off]     = make_float4(l[0], l[1], l[2], l[3]);
    *(float4*)&pl[off + 4] = make_float4(l[4], l[5], l[6], l[7]);
  }
}

// Kernel 2: split-softmax merge across D-chunks + bias term + output write.
// Two-pass (max first, then independent weighted sums) so all loads in the
// hot pass are latency-independent; unroll 8 for ILP.
__global__ __launch_bounds__(256)
void caps_k2(const float* __restrict__ psacc, const float* __restrict__ pt,
             const float* __restrict__ pm, const float* __restrict__ pl,
             float* __restrict__ out)
{
  const int tid = threadIdx.x;
  const int dq = tid & 15, c = tid >> 4;
  const int Bi = blockIdx.x & 63;
  const int dt = blockIdx.x >> 6;   // 256 blocks: (dt, Bi)

  // pass 1: global max over chunks (per (dt,dq,Bi); duplicated across c)
  float M = -INFINITY;
#pragma unroll 8
  for (int chn = 0; chn < NCHUNK; ++chn) {
    const size_t r = (size_t)(chn * 4 + dt) * 16 + dq;
    M = fmaxf(M, pm[r * 64 + Bi]);
  }
  // pass 2: all loads independent now
  float L = 0.f, acc = 0.f, tt = 0.f;
#pragma unroll 8
  for (int chn = 0; chn < NCHUNK; ++chn) {
    const size_t r = (size_t)(chn * 4 + dt) * 16 + dq;
    const float e = exp2f(pm[r * 64 + Bi] - M);
    L = fmaf(pl[r * 64 + Bi], e, L);
    const size_t ib = (r * 16 + c) * 64 + Bi;
    acc = fmaf(psacc[ib], e, acc);
    tt += pt[ib];
  }
  out[((size_t)Bi * 16 + c) * 64 + dt * 16 + dq] = acc / L + tt;
}

extern "C" void kernel_launch(void* const* d_in, const int* in_sizes, int n_in,
                              void* d_out, int out_size, void* d_ws, size_t ws_size,
                              hipStream_t stream)
{
  (void)in_sizes; (void)n_in; (void)out_size; (void)ws_size;
  const float* x    = (const float*)d_in[0];
  const float* w    = (const float*)d_in[1];
  const float* bias = (const float*)d_in[2];
  float* out = (float*)d_out;

  // Partials: per chunk 2*65536 (sacc,t) + 2*4096 (m,l) floats -> 71.3 MB total.
  float* psacc = (float*)d_ws;
  float* pt = psacc + (size_t)NCHUNK * 65536;
  float* pm = pt    + (size_t)NCHUNK * 65536;
  float* pl = pm    + (size_t)NCHUNK * 4096;

  hipLaunchKernelGGL(caps_k1, dim3(4 * NCHUNK), dim3(512), 0, stream,
                     x, w, bias, psacc, pt, pm, pl);
  hipLaunchKernelGGL(caps_k2, dim3(256), dim3(256), 0, stream,
                     psacc, pt, pm, pl, out);
}

// Round 8
// 213.825 us; speedup vs baseline: 1.7664x; 1.7664x over previous
//
#include <hip/hip_runtime.h>
#include <cstdint>
#include <cstddef>
#include <math.h>

// Problem: x(64,16,1152) w(16,16,1152,64) b(1152,64) -> out(64,16,64), f32.
// u = einsum(BCD,cCDd->BcDd); scores = sum_c u^2 / 4; attn = softmax_D(scores);
// out = einsum(BDd,BcDd->Bcd, attn + b, u).  Flash-style online softmax over D.
#define CDd 1179648   // c stride in w  (16*1152*64)
#define Dd_ 73728     // C stride in w  (1152*64)
#define XB_ 18432     // B stride in x  (16*1152)
#define NCHUNK 64
#define DSTEP 18      // 1152 / NCHUNK

__device__ __forceinline__ void async_dword(float* lds, const float* g) {
  __builtin_amdgcn_global_load_lds(
      (const __attribute__((address_space(1))) void*)g,
      (__attribute__((address_space(3))) void*)lds, 4, 0, 0);
}

// Kernel 1: fused projection + scores + online softmax + weighted accumulation
// over one D-chunk of 18, for all 64 B x 16 c x 16 d (one dtile of 4).
// Round-3 proven config: 109 us, VGPR=128 no spill, LDS 105 KB, 1 block/CU.
__global__ __launch_bounds__(512, 2)
void caps_k1(const float* __restrict__ x, const float* __restrict__ w,
             const float* __restrict__ bias,
             float* __restrict__ psacc, float* __restrict__ pt,
             float* __restrict__ pm, float* __restrict__ pl)
{
  __shared__ __align__(16) float ws[2][16 * 256];     // [C][dl*16+c], dbuf
  __shared__ __align__(16) float xs[16 * DSTEP * 64]; // [C][dd][b], once/chunk
  __shared__ __align__(16) float bs[DSTEP * 16];      // [dd][dl],  once/chunk

  const int tid  = threadIdx.x;
  const int lane = tid & 63;
  const int wv   = tid >> 6;        // wave 0..7
  const int b0   = (tid & 7) * 8;   // 8 B per thread
  const int c0   = ((tid >> 3) & 3) * 4; // 4 c per thread
  const int dl   = tid >> 5;        // d-within-tile 0..15

  const int dt = blockIdx.x >> 6;   // dtile 0..3 (16 d each)
  const int ch = blockIdx.x & 63;   // D-chunk; 4 dt of same ch share an XCD
  const int D0 = ch * DSTEP;

  const int wlane = (lane & 15) * CDd + (lane >> 4); // c*CDd + dl_sub

  // ---- once-per-chunk staging: x transpose-gather + bias ----
  for (int cc = 0; cc < 2; ++cc) {
    const int C = wv * 2 + cc;
    const float* gx = x + (size_t)lane * XB_ + C * 1152 + D0;
#pragma unroll
    for (int dd = 0; dd < DSTEP; ++dd)
      async_dword(&xs[(C * DSTEP + dd) * 64], gx + dd);
  }
  if (wv == 0) {
#pragma unroll
    for (int it = 0; it < 5; ++it) {
      const int flat = it * 64 + lane;
      if (flat < DSTEP * 16)
        async_dword(&bs[it * 64],
                    bias + (size_t)(D0 + (flat >> 4)) * 64 + dt * 16 + (flat & 15));
    }
  }

  auto stage_ws = [&](int s, int dd) {
#pragma unroll
    for (int cc = 0; cc < 2; ++cc) {
      const int C = wv * 2 + cc;
      const float* gw = w + (size_t)wlane + (size_t)C * Dd_
                          + (size_t)(D0 + dd) * 64 + dt * 16;
#pragma unroll
      for (int j = 0; j < 4; ++j)   // ws[C][dl*16+c] built by transpose gather
        async_dword(&ws[s][C * 256 + j * 64], gw + 4 * j);
    }
  };

  float sacc[8][4], tacc[8][4], m2[8], l[8];
#pragma unroll
  for (int i = 0; i < 8; ++i) {
    m2[i] = -INFINITY; l[i] = 0.f;
#pragma unroll
    for (int j = 0; j < 4; ++j) { sacc[i][j] = 0.f; tacc[i][j] = 0.f; }
  }

  stage_ws(0, 0);
  __syncthreads();
  int cur = 0;

  for (int dd = 0; dd < DSTEP; ++dd) {
    if (dd + 1 < DSTEP) stage_ws(cur ^ 1, dd + 1);  // async prefetch next D

    const float* wsT = ws[cur];
    const float bb = bs[dd * 16 + dl];

    float u[8][4];
#pragma unroll
    for (int C = 0; C < 16; ++C) {
      const float4 a0 = *(const float4*)&xs[(C * DSTEP + dd) * 64 + b0];
      const float4 a1 = *(const float4*)&xs[(C * DSTEP + dd) * 64 + b0 + 4];
      const float4 w0 = *(const float4*)&wsT[C * 256 + dl * 16 + c0];
      const float av[8] = {a0.x, a0.y, a0.z, a0.w, a1.x, a1.y, a1.z, a1.w};
      const float wn[4] = {w0.x, w0.y, w0.z, w0.w};
#pragma unroll
      for (int i = 0; i < 8; ++i)
#pragma unroll
        for (int j = 0; j < 4; ++j)
          u[i][j] = (C == 0) ? av[i] * wn[j] : fmaf(av[i], wn[j], u[i][j]);
    }

#pragma unroll
    for (int i = 0; i < 8; ++i) {
      float ps = 0.f;
#pragma unroll
      for (int j = 0; j < 4; ++j) ps = fmaf(u[i][j], u[i][j], ps);
      ps += __shfl_xor(ps, 8);       // sum over the 4 c-quarters
      ps += __shfl_xor(ps, 16);
      const float s2 = ps * 0.36067376022224085f;  // log2(e)/NC, NC=4
      const float mn = fmaxf(m2[i], s2);
      const float sc = exp2f(m2[i] - mn);
      const float p  = exp2f(s2 - mn);
      m2[i] = mn;
      l[i]  = fmaf(l[i], sc, p);
#pragma unroll
      for (int j = 0; j < 4; ++j) {
        sacc[i][j] = fmaf(sacc[i][j], sc, p * u[i][j]); // attn part (unnorm.)
        tacc[i][j] = fmaf(bb, u[i][j], tacc[i][j]);     // bias part (exact)
      }
    }
    __syncthreads();
    cur ^= 1;
  }

  // partials: psacc/pt [ch][dt][dl][c][b]; pm/pl [ch][dt][dl][b]
  const size_t rowB = (size_t)(ch * 4 + dt) * 16 + dl;
#pragma unroll
  for (int j = 0; j < 4; ++j) {
    const size_t off = (rowB * 16 + (c0 + j)) * 64 + b0;
    *(float4*)&psacc[off]     = make_float4(sacc[0][j], sacc[1][j], sacc[2][j], sacc[3][j]);
    *(float4*)&psacc[off + 4] = make_float4(sacc[4][j], sacc[5][j], sacc[6][j], sacc[7][j]);
    *(float4*)&pt[off]        = make_float4(tacc[0][j], tacc[1][j], tacc[2][j], tacc[3][j]);
    *(float4*)&pt[off + 4]    = make_float4(tacc[4][j], tacc[5][j], tacc[6][j], tacc[7][j]);
  }
  if (c0 == 0) {
    const size_t off = rowB * 64 + b0;
    *(float4*)&pm[off]     = make_float4(m2[0], m2[1], m2[2], m2[3]);
    *(float4*)&pm[off + 4] = make_float4(m2[4], m2[5], m2[6], m2[7]);
    *(float4*)&pl[off]     = make_float4(l[0], l[1], l[2], l[3]);
    *(float4*)&pl[off + 4] = make_float4(l[4], l[5], l[6], l[7]);
  }
}

// Kernel 2: split-softmax merge, COALESCED: lane = Bi (the partials' unit-
// stride axis), block = (dt, dl), 4 waves each owning 4 c values. Every
// psacc/pt/pm/pl access is a contiguous 256 B per wave; each partial element
// is read exactly once chip-wide (33.5 MB, LLC-resident after k1).
__global__ __launch_bounds__(256)
void caps_k2(const float* __restrict__ psacc, const float* __restrict__ pt,
             const float* __restrict__ pm, const float* __restrict__ pl,
             float* __restrict__ out)
{
  const int lane = threadIdx.x & 63;  // = Bi
  const int wv   = threadIdx.x >> 6;  // wave 0..3: c = wv*4 + cc
  const int dl = blockIdx.x & 15;
  const int dt = blockIdx.x >> 4;     // 64 blocks

  // pass 1: max over chunks (coalesced; wave-redundant, L1-shared)
  float M = -INFINITY;
#pragma unroll 4
  for (int ch = 0; ch < NCHUNK; ++ch) {
    const size_t r = (size_t)(ch * 4 + dt) * 16 + dl;
    M = fmaxf(M, pm[r * 64 + lane]);
  }

  float L = 0.f, acc[4] = {0.f, 0.f, 0.f, 0.f}, tt[4] = {0.f, 0.f, 0.f, 0.f};
#pragma unroll 4
  for (int ch = 0; ch < NCHUNK; ++ch) {
    const size_t r = (size_t)(ch * 4 + dt) * 16 + dl;
    const float e = exp2f(pm[r * 64 + lane] - M);
    L = fmaf(pl[r * 64 + lane], e, L);
#pragma unroll
    for (int cc = 0; cc < 4; ++cc) {
      const size_t ib = (r * 16 + (wv * 4 + cc)) * 64 + lane;
      acc[cc] = fmaf(psacc[ib], e, acc[cc]);
      tt[cc] += pt[ib];
    }
  }
  const float invL = 1.f / L;
#pragma unroll
  for (int cc = 0; cc < 4; ++cc)
    out[((size_t)lane * 16 + (wv * 4 + cc)) * 64 + dt * 16 + dl]
        = acc[cc] * invL + tt[cc];
}

extern "C" void kernel_launch(void* const* d_in, const int* in_sizes, int n_in,
                              void* d_out, int out_size, void* d_ws, size_t ws_size,
                              hipStream_t stream)
{
  (void)in_sizes; (void)n_in; (void)out_size; (void)ws_size;
  const float* x    = (const float*)d_in[0];
  const float* w    = (const float*)d_in[1];
  const float* bias = (const float*)d_in[2];
  float* out = (float*)d_out;

  // Partials: per chunk 2*65536 (sacc,t) + 2*4096 (m,l) floats -> 35.7 MB total.
  float* psacc = (float*)d_ws;
  float* pt = psacc + (size_t)NCHUNK * 65536;
  float* pm = pt    + (size_t)NCHUNK * 65536;
  float* pl = pm    + (size_t)NCHUNK * 4096;

  hipLaunchKernelGGL(caps_k1, dim3(4 * NCHUNK), dim3(512), 0, stream,
                     x, w, bias, psacc, pt, pm, pl);
  hipLaunchKernelGGL(caps_k2, dim3(64), dim3(256), 0, stream,
                     psacc, pt, pm, pl, out);
}